// Round 5
// baseline (10606.957 us; speedup 1.0000x reference)
//
#include <hip/hip_runtime.h>
#include <cstdint>
#include <cstddef>

#define L_SEQ 512
#define BATCH 64
#define EDIM  128
#define HDIM  256
#define GDIM  1024   // 4*HDIM
#define NTAGS 9

__device__ __forceinline__ float sigmoid_f(float x) { return 1.0f / (1.0f + expf(-x)); }

// ---------------- pack W_hh -> wp[dl][k][j] = (w[j][k], w[j+256][k], w[j+512][k], w[j+768][k]) ----
__global__ __launch_bounds__(256) void pack_whh_kernel(
    const float* __restrict__ w0f, const float* __restrict__ w0b,
    const float* __restrict__ w1f, const float* __restrict__ w1b,
    float4* __restrict__ wp)
{
    int k  = blockIdx.x;   // 0..255
    int dl = blockIdx.y;   // 0..3
    int j  = threadIdx.x;  // 0..255
    const float* w = (dl == 0) ? w0f : (dl == 1) ? w0b : (dl == 2) ? w1f : w1b;
    float4 v;
    v.x = w[(size_t)(j           ) * HDIM + k];
    v.y = w[(size_t)(j +   HDIM  ) * HDIM + k];
    v.z = w[(size_t)(j + 2*HDIM  ) * HDIM + k];
    v.w = w[(size_t)(j + 3*HDIM  ) * HDIM + k];
    wp[((size_t)dl * HDIM + k) * HDIM + j] = v;
}

// ---------------- fp32 GEMM chunk: C[m][n] = A[m][K] * B[n][K]^T + bias[n] ----------------
// Chunk rows m = tloc*64 + b. When `ids` is non-null (layer-0), A-row is gathered
// from emb[ids[b][off+tloc]] instead of A[m].
#define BMT 128
#define BNT 128
#define BKT 16
__global__ __launch_bounds__(256) void gemm_nt_bias(
    const float* __restrict__ A, const float* __restrict__ B,
    const float* __restrict__ bias, float* __restrict__ C,
    int N, int K,
    const int* __restrict__ ids, const float* __restrict__ emb, int off)
{
    __shared__ float As[BKT][BMT];
    __shared__ float Bs[BKT][BNT];
    int tid = threadIdx.x;
    int m0 = blockIdx.y * BMT;
    int n0 = blockIdx.x * BNT;
    int tx = tid & 15, ty = tid >> 4;
    int lr = tid >> 2;          // 0..63
    int lc = (tid & 3) * 4;     // 0,4,8,12

    int row0 = m0 + lr, row1 = m0 + lr + 64;
    const float *arow0, *arow1;
    if (ids != nullptr) {
        int t0 = off + (row0 >> 6), b0 = row0 & 63;
        int t1 = off + (row1 >> 6), b1 = row1 & 63;
        arow0 = emb + (size_t)ids[b0 * L_SEQ + t0] * EDIM;
        arow1 = emb + (size_t)ids[b1 * L_SEQ + t1] * EDIM;
    } else {
        arow0 = A + (size_t)row0 * K;
        arow1 = A + (size_t)row1 * K;
    }
    const float* brow0 = B + (size_t)(n0 + lr) * K;
    const float* brow1 = B + (size_t)(n0 + lr + 64) * K;

    float acc[8][8] = {};
    for (int k0 = 0; k0 < K; k0 += BKT) {
        float4 a0 = *(const float4*)&arow0[k0 + lc];
        float4 a1 = *(const float4*)&arow1[k0 + lc];
        float4 b0 = *(const float4*)&brow0[k0 + lc];
        float4 b1 = *(const float4*)&brow1[k0 + lc];
        __syncthreads();
        As[lc+0][lr] = a0.x; As[lc+1][lr] = a0.y; As[lc+2][lr] = a0.z; As[lc+3][lr] = a0.w;
        As[lc+0][lr+64] = a1.x; As[lc+1][lr+64] = a1.y; As[lc+2][lr+64] = a1.z; As[lc+3][lr+64] = a1.w;
        Bs[lc+0][lr] = b0.x; Bs[lc+1][lr] = b0.y; Bs[lc+2][lr] = b0.z; Bs[lc+3][lr] = b0.w;
        Bs[lc+0][lr+64] = b1.x; Bs[lc+1][lr+64] = b1.y; Bs[lc+2][lr+64] = b1.z; Bs[lc+3][lr+64] = b1.w;
        __syncthreads();
        #pragma unroll
        for (int kk = 0; kk < BKT; ++kk) {
            float a[8], bb[8];
            *(float4*)&a[0]  = *(const float4*)&As[kk][ty * 8];
            *(float4*)&a[4]  = *(const float4*)&As[kk][ty * 8 + 4];
            *(float4*)&bb[0] = *(const float4*)&Bs[kk][tx * 8];
            *(float4*)&bb[4] = *(const float4*)&Bs[kk][tx * 8 + 4];
            #pragma unroll
            for (int i = 0; i < 8; ++i)
                #pragma unroll
                for (int jj = 0; jj < 8; ++jj)
                    acc[i][jj] = fmaf(a[i], bb[jj], acc[i][jj]);
        }
    }
    float bo[8];
    *(float4*)&bo[0] = *(const float4*)&bias[n0 + tx * 8];
    *(float4*)&bo[4] = *(const float4*)&bias[n0 + tx * 8 + 4];
    #pragma unroll
    for (int i = 0; i < 8; ++i) {
        size_t row = (size_t)(m0 + ty * 8 + i);
        float4 o0 = make_float4(acc[i][0]+bo[0], acc[i][1]+bo[1], acc[i][2]+bo[2], acc[i][3]+bo[3]);
        float4 o1 = make_float4(acc[i][4]+bo[4], acc[i][5]+bo[5], acc[i][6]+bo[6], acc[i][7]+bo[7]);
        *(float4*)&C[row * N + n0 + tx * 8    ] = o0;
        *(float4*)&C[row * N + n0 + tx * 8 + 4] = o1;
    }
}

// ---------------- LSTM scan, one chunk of timesteps (chunk is runtime) ----------------
// 64 blocks = (dir 0/1) x (32 batch pairs), 512 threads = 256 j x 2 k-halves.
// dir0 advances t = off_f + s; dir1 advances t = off_b + chunk-1-s.
// Each thread loads each W_hh float4 ONCE, applies it to BOTH batch elems of its
// pair; k-dim split across thread halves; partials combined via LDS each step.
// (h,c) carried across chunk launches in stateH/stateC [dir*64+b][256].
__global__ __launch_bounds__(512) void lstm_scan_chunk(
    const float4* __restrict__ wpF, const float4* __restrict__ wpB,
    const float*  __restrict__ xpF, const float*  __restrict__ xpB,
    float* __restrict__ hcat,
    float* __restrict__ stateH, float* __restrict__ stateC,
    int off_f, int off_b, int first, int chunk)
{
    const int blk  = blockIdx.x;
    const int dir  = blk >> 5;          // 0 fwd, 1 bwd
    const int pair = blk & 31;
    const int tid  = threadIdx.x;
    const int ks   = tid >> 8;          // k-half selector (0: k<128, 1: k>=128)
    const int j    = tid & 255;         // hidden unit
    const int myb  = pair * 2 + ks;     // batch elem this thread owns state for
    const float4* wp = dir ? wpB : wpF;
    const float*  xp = dir ? xpB : xpF;
    const int sidx = (dir * BATCH + myb) * HDIM + j;

    __shared__ float4 hbuf4[2][2][HDIM / 4];   // [buf][b-half][k4]
    __shared__ float  part[2][256][8];         // [ks][j][{acc_b0, acc_b1}]

    float hl = first ? 0.0f : stateH[sidx];
    float c  = first ? 0.0f : stateC[sidx];
    ((float*)&hbuf4[0][ks][0])[j] = hl;
    __syncthreads();

    for (int s = 0; s < chunk; ++s) {
        const int tloc = dir ? (chunk - 1 - s) : s;             // row within chunk buffer
        const int t    = dir ? (off_b + chunk - 1 - s) : (off_f + s);  // global timestep
        const float4* h0 = &hbuf4[s & 1][0][0];
        const float4* h1 = &hbuf4[s & 1][1][0];
        float4 acc0 = make_float4(0.f, 0.f, 0.f, 0.f);
        float4 acc1 = make_float4(0.f, 0.f, 0.f, 0.f);
        #pragma unroll 4
        for (int kk = 0; kk < HDIM / 8; ++kk) {          // 32 k4-chunks per half
            const int k4 = ks * (HDIM / 8) + kk;
            const float4 hv0 = h0[k4];
            const float4 hv1 = h1[k4];
            const float4 w0 = wp[(k4 * 4 + 0) * HDIM + j];
            const float4 w1 = wp[(k4 * 4 + 1) * HDIM + j];
            const float4 w2 = wp[(k4 * 4 + 2) * HDIM + j];
            const float4 w3 = wp[(k4 * 4 + 3) * HDIM + j];
            acc0.x = fmaf(hv0.x, w0.x, acc0.x); acc0.y = fmaf(hv0.x, w0.y, acc0.y);
            acc0.z = fmaf(hv0.x, w0.z, acc0.z); acc0.w = fmaf(hv0.x, w0.w, acc0.w);
            acc0.x = fmaf(hv0.y, w1.x, acc0.x); acc0.y = fmaf(hv0.y, w1.y, acc0.y);
            acc0.z = fmaf(hv0.y, w1.z, acc0.z); acc0.w = fmaf(hv0.y, w1.w, acc0.w);
            acc0.x = fmaf(hv0.z, w2.x, acc0.x); acc0.y = fmaf(hv0.z, w2.y, acc0.y);
            acc0.z = fmaf(hv0.z, w2.z, acc0.z); acc0.w = fmaf(hv0.z, w2.w, acc0.w);
            acc0.x = fmaf(hv0.w, w3.x, acc0.x); acc0.y = fmaf(hv0.w, w3.y, acc0.y);
            acc0.z = fmaf(hv0.w, w3.z, acc0.z); acc0.w = fmaf(hv0.w, w3.w, acc0.w);
            acc1.x = fmaf(hv1.x, w0.x, acc1.x); acc1.y = fmaf(hv1.x, w0.y, acc1.y);
            acc1.z = fmaf(hv1.x, w0.z, acc1.z); acc1.w = fmaf(hv1.x, w0.w, acc1.w);
            acc1.x = fmaf(hv1.y, w1.x, acc1.x); acc1.y = fmaf(hv1.y, w1.y, acc1.y);
            acc1.z = fmaf(hv1.y, w1.z, acc1.z); acc1.w = fmaf(hv1.y, w1.w, acc1.w);
            acc1.x = fmaf(hv1.z, w2.x, acc1.x); acc1.y = fmaf(hv1.z, w2.y, acc1.y);
            acc1.z = fmaf(hv1.z, w2.z, acc1.z); acc1.w = fmaf(hv1.z, w2.w, acc1.w);
            acc1.x = fmaf(hv1.w, w3.x, acc1.x); acc1.y = fmaf(hv1.w, w3.y, acc1.y);
            acc1.z = fmaf(hv1.w, w3.z, acc1.z); acc1.w = fmaf(hv1.w, w3.w, acc1.w);
        }
        *(float4*)&part[ks][j][0] = acc0;
        *(float4*)&part[ks][j][4] = acc1;
        __syncthreads();
        // combine the two k-halves; thread (j, ks) finalizes batch elem ks of the pair
        float4 pa = *(const float4*)&part[0][j][ks * 4];
        float4 pb = *(const float4*)&part[1][j][ks * 4];
        const float* xr = xp + ((size_t)tloc * BATCH + myb) * GDIM;
        float zi = pa.x + pb.x + xr[j];
        float zf = pa.y + pb.y + xr[j +     HDIM];
        float zg = pa.z + pb.z + xr[j + 2 * HDIM];
        float zo = pa.w + pb.w + xr[j + 3 * HDIM];
        float ig = sigmoid_f(zi);
        float fg = sigmoid_f(zf);
        float gg = tanhf(zg);
        float og = sigmoid_f(zo);
        c = fmaf(fg, c, ig * gg);
        float h = og * tanhf(c);
        hl = h;
        ((float*)&hbuf4[(s + 1) & 1][ks][0])[j] = h;
        hcat[((size_t)t * BATCH + myb) * (2 * HDIM) + dir * HDIM + j] = h;
        __syncthreads();
    }
    stateH[sidx] = hl;
    stateC[sidx] = c;
}

// ---------------- classifier: preds[b][t][n] = H1[m=t*64+b] . cls_w[n] + cls_b[n] --------------
__global__ __launch_bounds__(288) void cls_kernel(
    const float* __restrict__ H1, const float* __restrict__ cw,
    const float* __restrict__ cb, float* __restrict__ out)
{
    int tid = threadIdx.x;
    int mi = tid / NTAGS, n = tid % NTAGS;   // mi 0..31
    int m = blockIdx.x * 32 + mi;
    const float* a = H1 + (size_t)m * 512;
    const float* w = cw + (size_t)n * 512;
    float acc = 0.0f;
    #pragma unroll 8
    for (int k = 0; k < 512; k += 4) {
        float4 av = *(const float4*)&a[k];
        float4 wv = *(const float4*)&w[k];
        acc = fmaf(av.x, wv.x, acc);
        acc = fmaf(av.y, wv.y, acc);
        acc = fmaf(av.z, wv.z, acc);
        acc = fmaf(av.w, wv.w, acc);
    }
    int b = m & 63, t = m >> 6;
    out[((size_t)b * L_SEQ + t) * NTAGS + n] = acc + cb[n];
}

// ---------------- CRF: numerator + normalizer + loss (one block, 9 waves) ----------------
__global__ __launch_bounds__(576) void crf_kernel(
    const float* __restrict__ preds, const int* __restrict__ labels,
    const int* __restrict__ amask, const float* __restrict__ startv,
    const float* __restrict__ endv, const float* __restrict__ trans,
    float* __restrict__ loss_out)
{
    const int tid = threadIdx.x;
    const int jw  = tid >> 6;      // tag j = wave id, 0..8
    const int b   = tid & 63;
    __shared__ float s_trans[NTAGS][NTAGS];
    __shared__ float s_start[NTAGS], s_end[NTAGS];
    __shared__ float sc[BATCH][NTAGS];
    __shared__ float red[BATCH][NTAGS];
    __shared__ float cntl[BATCH][NTAGS];
    __shared__ float norm_l[BATCH];
    __shared__ double llh_l[BATCH];
    if (tid < NTAGS * NTAGS) s_trans[tid / NTAGS][tid % NTAGS] = trans[tid];
    if (tid < NTAGS) { s_start[tid] = startv[tid]; s_end[tid] = endv[tid]; }
    __syncthreads();

    // ---- normalizer: forward algorithm in log space ----
    sc[b][jw] = s_start[jw] + preds[((size_t)b * L_SEQ + 0) * NTAGS + jw];
    __syncthreads();
    for (int t = 1; t < L_SEQ; ++t) {
        float em = preds[((size_t)b * L_SEQ + t) * NTAGS + jw];
        float v[NTAGS];
        float mx = -INFINITY;
        #pragma unroll
        for (int i = 0; i < NTAGS; ++i) {
            v[i] = sc[b][i] + s_trans[i][jw];
            mx = fmaxf(mx, v[i]);
        }
        float ssum = 0.0f;
        #pragma unroll
        for (int i = 0; i < NTAGS; ++i) ssum += expf(v[i] - mx);
        float nxt = mx + logf(ssum) + em;
        bool keep = amask[b * L_SEQ + t] != 0;
        float cur = sc[b][jw];
        __syncthreads();
        sc[b][jw] = keep ? nxt : cur;
        __syncthreads();
    }
    if (jw == 0) {
        float v[NTAGS];
        float mx = -INFINITY;
        #pragma unroll
        for (int i = 0; i < NTAGS; ++i) { v[i] = sc[b][i] + s_end[i]; mx = fmaxf(mx, v[i]); }
        float ssum = 0.0f;
        #pragma unroll
        for (int i = 0; i < NTAGS; ++i) ssum += expf(v[i] - mx);
        norm_l[b] = mx + logf(ssum);
    }

    // ---- numerator: gold-path score (t-parallel partials across the 9 waves) ----
    float part = 0.0f, cnt = 0.0f;
    for (int t = jw; t < L_SEQ; t += NTAGS)
        cnt += (amask[b * L_SEQ + t] != 0) ? 1.0f : 0.0f;
    for (int t = 1 + jw; t < L_SEQ; t += NTAGS) {
        if (amask[b * L_SEQ + t] != 0) {
            int tp = labels[b * L_SEQ + t - 1];
            int tc = labels[b * L_SEQ + t];
            part += s_trans[tp][tc] + preds[((size_t)b * L_SEQ + t) * NTAGS + tc];
        }
    }
    red[b][jw]  = part;
    cntl[b][jw] = cnt;
    __syncthreads();
    if (jw == 0) {
        float ssum = 0.0f, c2 = 0.0f;
        #pragma unroll
        for (int i = 0; i < NTAGS; ++i) { ssum += red[b][i]; c2 += cntl[b][i]; }
        int t0tag = labels[b * L_SEQ + 0];
        float num = s_start[t0tag] + preds[((size_t)b * L_SEQ + 0) * NTAGS + t0tag] + ssum;
        int se = (int)c2 - 1;
        int lastt = labels[b * L_SEQ + se];
        num += s_end[lastt];
        llh_l[b] = (double)num - (double)norm_l[b];
    }
    __syncthreads();
    if (tid == 0) {
        double s = 0.0;
        for (int i = 0; i < BATCH; ++i) s += llh_l[i];
        loss_out[0] = (float)(-s);
    }
}

extern "C" void kernel_launch(void* const* d_in, const int* in_sizes, int n_in,
                              void* d_out, int out_size, void* d_ws, size_t ws_size,
                              hipStream_t stream)
{
    const int*   ids    = (const int*)d_in[0];
    const int*   labels = (const int*)d_in[1];
    const int*   amask  = (const int*)d_in[2];
    const float* emb    = (const float*)d_in[3];
    const float* wih0f  = (const float*)d_in[4];
    const float* whh0f  = (const float*)d_in[5];
    const float* b0f    = (const float*)d_in[6];
    const float* wih0b  = (const float*)d_in[7];
    const float* whh0b  = (const float*)d_in[8];
    const float* b0b    = (const float*)d_in[9];
    const float* wih1f  = (const float*)d_in[10];
    const float* whh1f  = (const float*)d_in[11];
    const float* b1f    = (const float*)d_in[12];
    const float* wih1b  = (const float*)d_in[13];
    const float* whh1b  = (const float*)d_in[14];
    const float* b1b    = (const float*)d_in[15];
    const float* clsw   = (const float*)d_in[16];
    const float* clsb   = (const float*)d_in[17];
    const float* startv = (const float*)d_in[18];
    const float* endv   = (const float*)d_in[19];
    const float* transm = (const float*)d_in[20];
    float* out = (float*)d_out;
    (void)in_sizes; (void)n_in;

    // ---- adaptive chunk: largest power-of-two (<=64, >=2) whose layout fits ws_size.
    // Layout (floats): XPF chunk*65536 | XPB chunk*65536 | H0 16,777,216 | H1 16,777,216
    //                  | WP 1,048,576 | stateH 32,768 | stateC 32,768
    // Deterministic in ws_size -> identical work every call (graph-capture safe).
    const long long fixedf = 2LL * 16777216 + 1048576 + 2 * 32768;   // 34,668,544
    const long long availf = (long long)(ws_size / 4);
    int chunk = 64;
    while (chunk > 2 && fixedf + (long long)chunk * 131072 > availf) chunk >>= 1;
    const int nchunk = L_SEQ / chunk;

    float* ws    = (float*)d_ws;
    float* XPF_c = ws;                                   // [chunk*64][1024] gates, fwd
    float* XPB_c = XPF_c + (size_t)chunk * 65536;        // [chunk*64][1024] gates, bwd
    float* H0    = XPB_c + (size_t)chunk * 65536;        // [t][b][512]
    float* H1    = H0    + 16777216;                     // [t][b][512]
    float4* WP   = (float4*)(H1 + 16777216);             // packed W_hh, 4 x [256][256] float4
    float* stateH = (float*)(WP + 262144);               // [dir*64+b][256]
    float* stateC = stateH + 32768;

    float4* WP0F = WP;
    float4* WP0B = WP + 65536;
    float4* WP1F = WP + 131072;
    float4* WP1B = WP + 196608;

    pack_whh_kernel<<<dim3(256, 4), 256, 0, stream>>>(whh0f, whh0b, whh1f, whh1b, WP);

    const dim3 ggrid(GDIM / BNT, (chunk * BATCH) / BMT);   // (8, chunk/2)

    // ---- layer 0 (embedding gathered directly from emb via ids) ----
    for (int c = 0; c < nchunk; ++c) {
        int off_f = c * chunk;
        int off_b = (nchunk - 1 - c) * chunk;
        gemm_nt_bias<<<ggrid, 256, 0, stream>>>(nullptr, wih0f, b0f, XPF_c,
                                                GDIM, EDIM, ids, emb, off_f);
        gemm_nt_bias<<<ggrid, 256, 0, stream>>>(nullptr, wih0b, b0b, XPB_c,
                                                GDIM, EDIM, ids, emb, off_b);
        lstm_scan_chunk<<<64, 512, 0, stream>>>(WP0F, WP0B, XPF_c, XPB_c, H0,
                                                stateH, stateC, off_f, off_b, c == 0, chunk);
    }

    // ---- layer 1 ----
    for (int c = 0; c < nchunk; ++c) {
        int off_f = c * chunk;
        int off_b = (nchunk - 1 - c) * chunk;
        gemm_nt_bias<<<ggrid, 256, 0, stream>>>(H0 + (size_t)off_f * BATCH * 512,
                                                wih1f, b1f, XPF_c,
                                                GDIM, 512, nullptr, nullptr, 0);
        gemm_nt_bias<<<ggrid, 256, 0, stream>>>(H0 + (size_t)off_b * BATCH * 512,
                                                wih1b, b1b, XPB_c,
                                                GDIM, 512, nullptr, nullptr, 0);
        lstm_scan_chunk<<<64, 512, 0, stream>>>(WP1F, WP1B, XPF_c, XPB_c, H1,
                                                stateH, stateC, off_f, off_b, c == 0, chunk);
    }

    cls_kernel<<<1024, 288, 0, stream>>>(H1, clsw, clsb, out);
    crf_kernel<<<1, 576, 0, stream>>>(out, labels, amask, startv, endv, transm,
                                      out + (out_size - 1));
}